// Round 1
// baseline (3473.542 us; speedup 1.0000x reference)
//
#include <hip/hip_runtime.h>

#define N_NODES   50000
#define N_HEDGES  100000
#define E_EDGES   800000
#define F_IN      128
#define F_H       64
#define F_OUT     128

// ---------------------------------------------------------------------------
// Kernel 0: binary-search per-node edge ranges in the two sorted receiver
// arrays. offs[r] = first edge index with receiver >= r; offs[N_NODES] = E.
// ---------------------------------------------------------------------------
__global__ __launch_bounds__(256)
void offsets_kernel(const int* __restrict__ recv1, const int* __restrict__ recv2,
                    int* __restrict__ offs1, int* __restrict__ offs2) {
    int t = blockIdx.x * blockDim.x + threadIdx.x;
    const int total = N_NODES + 1;
    if (t < total) {
        int r = t, lo = 0, hi = E_EDGES;
        while (lo < hi) { int mid = (lo + hi) >> 1; if (recv1[mid] < r) lo = mid + 1; else hi = mid; }
        offs1[r] = lo;
    } else if (t < 2 * total) {
        int r = t - total, lo = 0, hi = E_EDGES;
        while (lo < hi) { int mid = (lo + hi) >> 1; if (recv2[mid] < r) lo = mid + 1; else hi = mid; }
        offs2[r] = lo;
    }
}

// ---------------------------------------------------------------------------
// Kernel 1: Acc1[r][f] = sum_{e: recv[e]==r} conv[e] * nf[snd[e]][f]
// 128 threads per node (one per feature) -> each edge is a coalesced 512B row
// read. Also Csum1[r] = sum conv[e] (for the bias term).
// ---------------------------------------------------------------------------
__global__ __launch_bounds__(256)
void gather_nodes_kernel(const float* __restrict__ nf, const int* __restrict__ senders,
                         const float* __restrict__ conv, const int* __restrict__ offs,
                         float* __restrict__ acc_out, float* __restrict__ csum_out) {
    int group = (blockIdx.x << 1) + (threadIdx.x >> 7);   // node id
    int f = threadIdx.x & 127;
    if (group >= N_NODES) return;
    int s = offs[group], e = offs[group + 1];
    float acc = 0.f, cs = 0.f;
    int i = s;
    for (; i + 4 <= e; i += 4) {                           // 4-deep MLP
        int   s0 = senders[i],   s1 = senders[i+1], s2 = senders[i+2], s3 = senders[i+3];
        float c0 = conv[i],      c1 = conv[i+1],    c2 = conv[i+2],    c3 = conv[i+3];
        float v0 = nf[s0 * F_IN + f], v1 = nf[s1 * F_IN + f];
        float v2 = nf[s2 * F_IN + f], v3 = nf[s3 * F_IN + f];
        acc += c0 * v0; acc += c1 * v1; acc += c2 * v2; acc += c3 * v3;
        cs  += c0 + c1 + c2 + c3;
    }
    for (; i < e; ++i) {
        int sn = senders[i]; float c = conv[i];
        acc += c * nf[sn * F_IN + f]; cs += c;
    }
    acc_out[group * F_IN + f] = acc;
    if (f == 0) csum_out[group] = cs;
}

// ---------------------------------------------------------------------------
// Kernel 2: same for hedge pipeline, 64 threads per node (F_H = 64).
// ---------------------------------------------------------------------------
__global__ __launch_bounds__(256)
void gather_hedges_kernel(const float* __restrict__ hf, const int* __restrict__ senders,
                          const float* __restrict__ conv, const int* __restrict__ offs,
                          float* __restrict__ acc_out, float* __restrict__ csum_out) {
    int group = (blockIdx.x << 2) + (threadIdx.x >> 6);
    int f = threadIdx.x & 63;
    if (group >= N_NODES) return;
    int s = offs[group], e = offs[group + 1];
    float acc = 0.f, cs = 0.f;
    int i = s;
    for (; i + 4 <= e; i += 4) {
        int   s0 = senders[i],   s1 = senders[i+1], s2 = senders[i+2], s3 = senders[i+3];
        float c0 = conv[i],      c1 = conv[i+1],    c2 = conv[i+2],    c3 = conv[i+3];
        float v0 = hf[s0 * F_H + f], v1 = hf[s1 * F_H + f];
        float v2 = hf[s2 * F_H + f], v3 = hf[s3 * F_H + f];
        acc += c0 * v0; acc += c1 * v1; acc += c2 * v2; acc += c3 * v3;
        cs  += c0 + c1 + c2 + c3;
    }
    for (; i < e; ++i) {
        int sn = senders[i]; float c = conv[i];
        acc += c * hf[sn * F_H + f]; cs += c;
    }
    acc_out[group * F_H + f] = acc;
    if (f == 0) csum_out[group] = cs;
}

// ---------------------------------------------------------------------------
// Kernel 3: out[r][j] = tanh( (Acc2[r]@Wsᵀ + Cs2[r]*bs)[j]
//                           * (Acc1[r]@Wmᵀ + Cs1[r]*bm)[j] )
// 512 threads = 4 groups x 128 output-features. W in LDS, row-padded +1 float
// -> bank (j+k)%32, conflict-free. Acc staged transposed [k][node4] so one
// broadcast ds_read_b128 feeds 4 FMAs. NOTE: acc1g aliases `out` (safe: each
// block stages a quad's rows fully before overwriting them).
// ---------------------------------------------------------------------------
__global__ __launch_bounds__(512)
void gemm_tanh_kernel(const float* acc1g,                       // aliases out!
                      const float* __restrict__ acc2g,
                      const float* __restrict__ csum1, const float* __restrict__ csum2,
                      const float* __restrict__ Wm,  const float* __restrict__ bm,
                      const float* __restrict__ Wsc, const float* __restrict__ bs,
                      float* outp) {
    __shared__ float lWm[F_OUT * (F_IN + 1)];    // [j][k] padded: 66048 B
    __shared__ float lWs[F_OUT * (F_H + 1)];     // [j][k] padded: 33280 B
    __shared__ float laT1[4][F_IN * 4];          // per group: [k][n]  8192 B
    __shared__ float laT2[4][F_H * 4];           //                    4096 B
    __shared__ float lcs[4][8];                  // cs1[0..3] cs2[4..7]

    int tid = threadIdx.x;
    // stage W_msg (16384 floats, float4 x 512 threads x 8 iters)
    #pragma unroll
    for (int it = 0; it < 8; ++it) {
        int idx = (it * 512 + tid) * 4;
        int j = idx >> 7, k0 = idx & 127;
        float4 w = *(const float4*)(Wm + idx);
        float* p = &lWm[j * (F_IN + 1) + k0];
        p[0] = w.x; p[1] = w.y; p[2] = w.z; p[3] = w.w;
    }
    // stage W_scale (8192 floats)
    #pragma unroll
    for (int it = 0; it < 4; ++it) {
        int idx = (it * 512 + tid) * 4;
        int j = idx >> 6, k0 = idx & 63;
        float4 w = *(const float4*)(Wsc + idx);
        float* p = &lWs[j * (F_H + 1) + k0];
        p[0] = w.x; p[1] = w.y; p[2] = w.z; p[3] = w.w;
    }

    int g = tid >> 7;          // group 0..3
    int j = tid & 127;         // output feature
    float bmj = bm[j], bsj = bs[j];
    int base = blockIdx.x * 64 + g * 16;
    __syncthreads();

    for (int q = 0; q < 4; ++q) {
        int n0 = base + q * 4;
        // stage accumulator quad (transposed)
        #pragma unroll
        for (int n = 0; n < 4; ++n) {
            int node = n0 + n;
            if (node < N_NODES) {
                laT1[g][j * 4 + n] = acc1g[node * F_IN + j];
                if (j < F_H) laT2[g][j * 4 + n] = acc2g[node * F_H + j];
                if (j == 0) { lcs[g][n] = csum1[node]; lcs[g][4 + n] = csum2[node]; }
            }
        }
        __syncthreads();

        float m0 = lcs[g][0] * bmj, m1 = lcs[g][1] * bmj,
              m2 = lcs[g][2] * bmj, m3 = lcs[g][3] * bmj;
        float s0 = lcs[g][4] * bsj, s1 = lcs[g][5] * bsj,
              s2 = lcs[g][6] * bsj, s3 = lcs[g][7] * bsj;

        const float* wrow = &lWm[j * (F_IN + 1)];
        const float* a1   = laT1[g];
        #pragma unroll
        for (int k = 0; k < F_IN; ++k) {
            float  w = wrow[k];
            float4 a = *(const float4*)(a1 + k * 4);   // broadcast read
            m0 += w * a.x; m1 += w * a.y; m2 += w * a.z; m3 += w * a.w;
        }
        const float* wrow2 = &lWs[j * (F_H + 1)];
        const float* a2    = laT2[g];
        #pragma unroll
        for (int k = 0; k < F_H; ++k) {
            float  w = wrow2[k];
            float4 a = *(const float4*)(a2 + k * 4);
            s0 += w * a.x; s1 += w * a.y; s2 += w * a.z; s3 += w * a.w;
        }

        if (n0 + 0 < N_NODES) outp[(n0 + 0) * F_OUT + j] = tanhf(m0 * s0);
        if (n0 + 1 < N_NODES) outp[(n0 + 1) * F_OUT + j] = tanhf(m1 * s1);
        if (n0 + 2 < N_NODES) outp[(n0 + 2) * F_OUT + j] = tanhf(m2 * s2);
        if (n0 + 3 < N_NODES) outp[(n0 + 3) * F_OUT + j] = tanhf(m3 * s3);
        __syncthreads();
    }
}

// ---------------------------------------------------------------------------
extern "C" void kernel_launch(void* const* d_in, const int* in_sizes, int n_in,
                              void* d_out, int out_size, void* d_ws, size_t ws_size,
                              hipStream_t stream) {
    const float* node_features  = (const float*)d_in[0];
    const float* hedge_features = (const float*)d_in[1];
    const int*   node_senders   = (const int*)d_in[2];
    const int*   node_receivers = (const int*)d_in[3];
    const float* node_conv      = (const float*)d_in[4];
    const int*   h2n_senders    = (const int*)d_in[5];
    const int*   h2n_receivers  = (const int*)d_in[6];
    const float* h2n_conv       = (const float*)d_in[7];
    const float* W_msg          = (const float*)d_in[8];
    const float* b_msg          = (const float*)d_in[9];
    const float* W_scale        = (const float*)d_in[10];
    const float* b_scale        = (const float*)d_in[11];

    float* out = (float*)d_out;
    char*  ws  = (char*)d_ws;

    // ws layout (Acc1 lives in d_out itself)
    float* Acc2  = (float*)(ws);                    // 12,800,000 B
    float* Csum1 = (float*)(ws + 12800000);         //    200,000 B
    float* Csum2 = (float*)(ws + 13000000);         //    200,000 B
    int*   offs1 = (int*)  (ws + 13200000);         //    200,016 B
    int*   offs2 = (int*)  (ws + 13400016);         //    200,016 B
    float* Acc1  = out;

    offsets_kernel<<<(2 * (N_NODES + 1) + 255) / 256, 256, 0, stream>>>(
        node_receivers, h2n_receivers, offs1, offs2);

    gather_nodes_kernel<<<N_NODES / 2, 256, 0, stream>>>(
        node_features, node_senders, node_conv, offs1, Acc1, Csum1);

    gather_hedges_kernel<<<N_NODES / 4, 256, 0, stream>>>(
        hedge_features, h2n_senders, h2n_conv, offs2, Acc2, Csum2);

    gemm_tanh_kernel<<<(N_NODES + 63) / 64, 512, 0, stream>>>(
        Acc1, Acc2, Csum1, Csum2, W_msg, b_msg, W_scale, b_scale, out);
}

// Round 2
// 245.583 us; speedup vs baseline: 14.1441x; 14.1441x over previous
//
#include <hip/hip_runtime.h>

#define N_NODES   50000
#define N_HEDGES  100000
#define E_EDGES   800000
#define F_IN      128
#define F_H       64
#define F_OUT     128

// ---------------------------------------------------------------------------
// Kernel 0: binary-search per-node edge ranges in the two sorted receiver
// arrays. offs[r] = first edge index with receiver >= r; offs[N_NODES] = E.
// ---------------------------------------------------------------------------
__global__ __launch_bounds__(256)
void offsets_kernel(const int* __restrict__ recv1, const int* __restrict__ recv2,
                    int* __restrict__ offs1, int* __restrict__ offs2) {
    int t = blockIdx.x * blockDim.x + threadIdx.x;
    const int total = N_NODES + 1;
    if (t < total) {
        int r = t, lo = 0, hi = E_EDGES;
        while (lo < hi) { int mid = (lo + hi) >> 1; if (recv1[mid] < r) lo = mid + 1; else hi = mid; }
        offs1[r] = lo;
    } else if (t < 2 * total) {
        int r = t - total, lo = 0, hi = E_EDGES;
        while (lo < hi) { int mid = (lo + hi) >> 1; if (recv2[mid] < r) lo = mid + 1; else hi = mid; }
        offs2[r] = lo;
    }
}

// ---------------------------------------------------------------------------
// Kernel 1: Acc1[r][f] = sum_{e: recv[e]==r} conv[e] * nf[snd[e]][f]
// 128 threads per node (one per feature) -> each edge is a coalesced 512B row
// read. Also Csum1[r] = sum conv[e] (for the bias term).
// ---------------------------------------------------------------------------
__global__ __launch_bounds__(256)
void gather_nodes_kernel(const float* __restrict__ nf, const int* __restrict__ senders,
                         const float* __restrict__ conv, const int* __restrict__ offs,
                         float* __restrict__ acc_out, float* __restrict__ csum_out) {
    int group = (blockIdx.x << 1) + (threadIdx.x >> 7);   // node id
    int f = threadIdx.x & 127;
    if (group >= N_NODES) return;
    int s = offs[group], e = offs[group + 1];
    float acc = 0.f, cs = 0.f;
    int i = s;
    for (; i + 4 <= e; i += 4) {                           // 4-deep MLP
        int   s0 = senders[i],   s1 = senders[i+1], s2 = senders[i+2], s3 = senders[i+3];
        float c0 = conv[i],      c1 = conv[i+1],    c2 = conv[i+2],    c3 = conv[i+3];
        float v0 = nf[s0 * F_IN + f], v1 = nf[s1 * F_IN + f];
        float v2 = nf[s2 * F_IN + f], v3 = nf[s3 * F_IN + f];
        acc += c0 * v0; acc += c1 * v1; acc += c2 * v2; acc += c3 * v3;
        cs  += c0 + c1 + c2 + c3;
    }
    for (; i < e; ++i) {
        int sn = senders[i]; float c = conv[i];
        acc += c * nf[sn * F_IN + f]; cs += c;
    }
    acc_out[group * F_IN + f] = acc;
    if (f == 0) csum_out[group] = cs;
}

// ---------------------------------------------------------------------------
// Kernel 2: same for hedge pipeline, 64 threads per node (F_H = 64).
// ---------------------------------------------------------------------------
__global__ __launch_bounds__(256)
void gather_hedges_kernel(const float* __restrict__ hf, const int* __restrict__ senders,
                          const float* __restrict__ conv, const int* __restrict__ offs,
                          float* __restrict__ acc_out, float* __restrict__ csum_out) {
    int group = (blockIdx.x << 2) + (threadIdx.x >> 6);
    int f = threadIdx.x & 63;
    if (group >= N_NODES) return;
    int s = offs[group], e = offs[group + 1];
    float acc = 0.f, cs = 0.f;
    int i = s;
    for (; i + 4 <= e; i += 4) {
        int   s0 = senders[i],   s1 = senders[i+1], s2 = senders[i+2], s3 = senders[i+3];
        float c0 = conv[i],      c1 = conv[i+1],    c2 = conv[i+2],    c3 = conv[i+3];
        float v0 = hf[s0 * F_H + f], v1 = hf[s1 * F_H + f];
        float v2 = hf[s2 * F_H + f], v3 = hf[s3 * F_H + f];
        acc += c0 * v0; acc += c1 * v1; acc += c2 * v2; acc += c3 * v3;
        cs  += c0 + c1 + c2 + c3;
    }
    for (; i < e; ++i) {
        int sn = senders[i]; float c = conv[i];
        acc += c * hf[sn * F_H + f]; cs += c;
    }
    acc_out[group * F_H + f] = acc;
    if (f == 0) csum_out[group] = cs;
}

// ---------------------------------------------------------------------------
// Kernel 3 (REWRITTEN): weights-in-registers node-level dual matvec + tanh.
// Thread t: output feature j = t>>1, half h = t&1. Holds W_msg[j][h*64..+64)
// and W_scale[j][h*32..+32) in VGPRs. Per node: acc rows staged in tiny
// double-buffered LDS (1.6 KB), broadcast ds_read_b128, 96 FMA/thread,
// pair-reduce via shfl_xor(1), even lane writes tanh(m*s).
// acc1g aliases outp: row n is fully staged before out row n is written.
// ---------------------------------------------------------------------------
__global__ __launch_bounds__(256)
void gemm_tanh_kernel(const float* acc1g,                       // aliases out!
                      const float* __restrict__ acc2g,
                      const float* __restrict__ csum1, const float* __restrict__ csum2,
                      const float* __restrict__ Wm,  const float* __restrict__ bm,
                      const float* __restrict__ Wsc, const float* __restrict__ bs,
                      float* outp, int nodes_per_block) {
    const int t = threadIdx.x;
    const int j = t >> 1;          // output feature 0..127
    const int h = t & 1;           // k-range half

    // --- load weight slices into registers (coalesced float4) ---
    float wm[64], ws_[32];
    const float* wmrow = Wm + j * F_IN + h * 64;
    #pragma unroll
    for (int k = 0; k < 16; ++k) {
        float4 v = *(const float4*)(wmrow + k * 4);
        wm[k*4+0] = v.x; wm[k*4+1] = v.y; wm[k*4+2] = v.z; wm[k*4+3] = v.w;
    }
    const float* wsrow = Wsc + j * F_H + h * 32;
    #pragma unroll
    for (int k = 0; k < 8; ++k) {
        float4 v = *(const float4*)(wsrow + k * 4);
        ws_[k*4+0] = v.x; ws_[k*4+1] = v.y; ws_[k*4+2] = v.z; ws_[k*4+3] = v.w;
    }
    const float bmj = bm[j], bsj = bs[j];

    __shared__ float sA1[2][F_IN];
    __shared__ float sA2[2][F_H];
    __shared__ float sCs[2][2];

    const int n0 = blockIdx.x * nodes_per_block;
    const int n1 = min(n0 + nodes_per_block, N_NODES);
    if (n0 >= n1) return;

    // stage node n into buffer buf
    auto stage = [&](int buf, int n) {
        if (t < 128)       sA1[buf][t]       = acc1g[n * F_IN + t];
        else if (t < 192)  sA2[buf][t - 128] = acc2g[n * F_H + (t - 128)];
        else if (t == 192) sCs[buf][0] = csum1[n];
        else if (t == 193) sCs[buf][1] = csum2[n];
    };

    stage(0, n0);
    int cur = 0;
    for (int n = n0; n < n1; ++n) {
        __syncthreads();                       // staging of `cur` complete
        if (n + 1 < n1) stage(cur ^ 1, n + 1); // prefetch next node
        // --- compute from buffer `cur` ---
        float m = 0.f, s = 0.f;
        const float* a1 = &sA1[cur][h * 64];
        #pragma unroll
        for (int k = 0; k < 16; ++k) {
            float4 a = *(const float4*)(a1 + k * 4);   // broadcast read
            m += wm[k*4+0] * a.x; m += wm[k*4+1] * a.y;
            m += wm[k*4+2] * a.z; m += wm[k*4+3] * a.w;
        }
        const float* a2 = &sA2[cur][h * 32];
        #pragma unroll
        for (int k = 0; k < 8; ++k) {
            float4 a = *(const float4*)(a2 + k * 4);
            s += ws_[k*4+0] * a.x; s += ws_[k*4+1] * a.y;
            s += ws_[k*4+2] * a.z; s += ws_[k*4+3] * a.w;
        }
        float cs1 = sCs[cur][0], cs2 = sCs[cur][1];
        m += __shfl_xor(m, 1);                 // combine halves
        s += __shfl_xor(s, 1);
        if (h == 0) {
            float mt = m + cs1 * bmj;
            float st = s + cs2 * bsj;
            outp[n * F_OUT + j] = tanhf(mt * st);
        }
        cur ^= 1;
    }
}

// ---------------------------------------------------------------------------
extern "C" void kernel_launch(void* const* d_in, const int* in_sizes, int n_in,
                              void* d_out, int out_size, void* d_ws, size_t ws_size,
                              hipStream_t stream) {
    const float* node_features  = (const float*)d_in[0];
    const float* hedge_features = (const float*)d_in[1];
    const int*   node_senders   = (const int*)d_in[2];
    const int*   node_receivers = (const int*)d_in[3];
    const float* node_conv      = (const float*)d_in[4];
    const int*   h2n_senders    = (const int*)d_in[5];
    const int*   h2n_receivers  = (const int*)d_in[6];
    const float* h2n_conv       = (const float*)d_in[7];
    const float* W_msg          = (const float*)d_in[8];
    const float* b_msg          = (const float*)d_in[9];
    const float* W_scale        = (const float*)d_in[10];
    const float* b_scale        = (const float*)d_in[11];

    float* out = (float*)d_out;
    char*  ws  = (char*)d_ws;

    // ws layout (Acc1 lives in d_out itself)
    float* Acc2  = (float*)(ws);                    // 12,800,000 B
    float* Csum1 = (float*)(ws + 12800000);         //    200,000 B
    float* Csum2 = (float*)(ws + 13000000);         //    200,000 B
    int*   offs1 = (int*)  (ws + 13200000);         //    200,016 B
    int*   offs2 = (int*)  (ws + 13400016);         //    200,016 B
    float* Acc1  = out;

    offsets_kernel<<<(2 * (N_NODES + 1) + 255) / 256, 256, 0, stream>>>(
        node_receivers, h2n_receivers, offs1, offs2);

    gather_nodes_kernel<<<N_NODES / 2, 256, 0, stream>>>(
        node_features, node_senders, node_conv, offs1, Acc1, Csum1);

    gather_hedges_kernel<<<N_NODES / 4, 256, 0, stream>>>(
        hedge_features, h2n_senders, h2n_conv, offs2, Acc2, Csum2);

    const int nodes_per_block = 49;                  // 1021 blocks
    gemm_tanh_kernel<<<(N_NODES + nodes_per_block - 1) / nodes_per_block, 256, 0, stream>>>(
        Acc1, Acc2, Csum1, Csum2, W_msg, b_msg, W_scale, b_scale, out, nodes_per_block);
}